// Round 1
// baseline (834.830 us; speedup 1.0000x reference)
//
#include <hip/hip_runtime.h>
#include <math.h>

#define B_ 32
#define T_ 2048
#define H_ 1024

typedef __bf16 bf16x8 __attribute__((ext_vector_type(8)));
typedef float f32x4 __attribute__((ext_vector_type(4)));

__device__ __forceinline__ unsigned short f2bf(float f) {
  unsigned int u = __float_as_uint(f);
  u += 0x7fffu + ((u >> 16) & 1u);   // round-to-nearest-even (finite inputs)
  return (unsigned short)(u >> 16);
}

__device__ __forceinline__ float bf2f(unsigned short s) {
  return __uint_as_float(((unsigned int)s) << 16);
}

__device__ __forceinline__ float fast_tanh(float x) {
  float e = __expf(2.0f * x);
  return 1.0f - __fdividef(2.0f, e + 1.0f);  // saturates correctly at +-1
}

// Async 16B global -> LDS. LDS dest is wave-uniform base + lane*16 (HW rule);
// generic->AS casts via integers (LDS generic addr low 32 bits = LDS offset).
__device__ __forceinline__ void async16(const void* g, void* l) {
  typedef const __attribute__((address_space(1))) void* gvp;
  typedef __attribute__((address_space(3))) void* lvp;
  __builtin_amdgcn_global_load_lds((gvp)(unsigned long long)g,
                                   (lvp)(unsigned int)(unsigned long long)l,
                                   16, 0, 0);
}

// blk ranges:
//  [0,256):      hxb — wave per o: loads Wq row ONCE, loops b (Wq read 4 MB total, not 128 MB)
//  [256,1280):   Wm fp32 -> bf16
//  [1280,1312):  zero out_c (32 blocks); block 1280 also zeroes den[32]
//  [1312,34080): ctx fp32 -> bf16 (only when ws has room)
__global__ void prep_kernel(const float* __restrict__ x, const float* __restrict__ Wq,
                            const float* __restrict__ bq, const float* __restrict__ bm,
                            const float* __restrict__ Wm, const float* __restrict__ ctx,
                            float* __restrict__ hxb, unsigned short* __restrict__ wmb,
                            unsigned short* __restrict__ ctxb,
                            float* __restrict__ den, float* __restrict__ outc) {
  int blk = blockIdx.x, tid = threadIdx.x;
  if (blk < 256) {
    int wave = tid >> 6, lane = tid & 63;
    int o = (blk << 2) + wave;
    const float4* wr = (const float4*)(Wq + (size_t)o * H_);
    float4 wv[4];
#pragma unroll
    for (int s4 = 0; s4 < 4; ++s4) wv[s4] = wr[(s4 << 6) + lane];
    float bias = bq[o] + bm[o];
#pragma unroll 4
    for (int b = 0; b < B_; ++b) {
      const float4* xr = (const float4*)(x + (size_t)b * H_);
      float s = 0.f;
#pragma unroll
      for (int s4 = 0; s4 < 4; ++s4) {
        float4 xv = xr[(s4 << 6) + lane];
        s += wv[s4].x * xv.x + wv[s4].y * xv.y + wv[s4].z * xv.z + wv[s4].w * xv.w;
      }
#pragma unroll
      for (int d = 1; d < 64; d <<= 1) s += __shfl_xor(s, d);
      if (lane == 0) hxb[(b << 10) + o] = s + bias;
    }
  } else if (blk < 1280) {
    int i = ((blk - 256) << 10) + (tid << 2);
    float4 wv = *(const float4*)(Wm + i);
    *(ushort4*)(wmb + i) = make_ushort4(f2bf(wv.x), f2bf(wv.y), f2bf(wv.z), f2bf(wv.w));
  } else if (blk < 1312) {
    int zb = blk - 1280;
    *(float4*)(outc + (zb << 10) + (tid << 2)) = (float4){0.f, 0.f, 0.f, 0.f};
    if (zb == 0 && tid < B_) den[tid] = 0.f;
  } else {
    size_t i = ((size_t)(blk - 1312) << 11) + ((size_t)tid << 3);
    float4 a = *(const float4*)(ctx + i);
    float4 c = *(const float4*)(ctx + i + 4);
    *(ushort4*)(ctxb + i) = make_ushort4(f2bf(a.x), f2bf(a.y), f2bf(a.z), f2bf(a.w));
    *(ushort4*)(ctxb + i + 4) = make_ushort4(f2bf(c.x), f2bf(c.y), f2bf(c.z), f2bf(c.w));
  }
}

// Fused: grid 512 = b*16 + tb. Block owns 128 t-rows x FULL o-range (8 chunks of 128).
// For each o-chunk: K-loop GEMM (LDS-staged, XOR-swizzled, global_load_lds), epilogue
// tanh(.)+v-dot accumulated into part[128] (LDS). After all chunks: logits complete ->
// unnormalized e^l written to score out, sum atomically added to den[b], then the
// (cache-hot) ctx tile is weighted-summed straight into out_c numerator via atomics.
// No max-shift needed: |logit| <= sum|v| ~ 26, exp stays in fp32 range.
template <bool PRECONV>
__global__ __launch_bounds__(256) void score_kernel(
    const float* __restrict__ ctxf, const unsigned short* __restrict__ ctxb,
    const unsigned short* __restrict__ wmb,
    const float* __restrict__ hxb, const float* __restrict__ v,
    float* __restrict__ outs, float* __restrict__ outc, float* __restrict__ den) {
  __shared__ __align__(16) unsigned short As[128 * 64];
  __shared__ __align__(16) unsigned short Bs[128 * 64];
  __shared__ float part[128];

  int tid = threadIdx.x;
  int bx = blockIdx.x;
  int b = bx >> 4;
  int t0 = (bx & 15) << 7;

  if (tid < 128) part[tid] = 0.f;

  int lane = tid & 63;
  int wave = tid >> 6;
  int wm = (wave >> 1) << 6;  // wave t-offset (0/64)
  int wn = (wave & 1) << 6;   // wave o-offset (0/64)
  int q = lane >> 4;
  int m = lane & 15;

  const unsigned short* cb = PRECONV ? (ctxb + ((size_t)b * T_ + t0) * H_) : nullptr;
  const float* cf = PRECONV ? nullptr : (ctxf + ((size_t)b * T_ + t0) * H_);

  for (int oc = 0; oc < 8; ++oc) {
    int o0 = oc << 7;
    const unsigned short* wb = wmb + (size_t)o0 * H_;

    f32x4 acc[4][4];
#pragma unroll
    for (int i = 0; i < 4; ++i)
#pragma unroll
      for (int j = 0; j < 4; ++j) acc[i][j] = (f32x4){0.f, 0.f, 0.f, 0.f};

    for (int k0 = 0; k0 < H_; k0 += 64) {
      __syncthreads();
#pragma unroll
      for (int i = 0; i < 4; ++i) {
        int ig = (wave << 2) + i;          // issue-group 0..15 (64 granules each)
        int p = (ig << 6) + lane;          // physical granule 0..1023
        int row = p >> 3;
        int gl = (p & 7) ^ (row & 7);      // logical granule (swizzle inverse)
        size_t goff = (size_t)row * H_ + k0 + (gl << 3);
        if (PRECONV) {
          async16(cb + goff, (char*)As + ((size_t)ig << 10));
        } else {
          int arow = (tid >> 3) + (i << 5);
          int agl = tid & 7;
          int agp = agl ^ (arow & 7);
          const float* src = cf + (size_t)arow * H_ + k0 + (agl << 3);
          float4 f0 = *(const float4*)(src);
          float4 f1 = *(const float4*)(src + 4);
          unsigned short* dst = As + (arow << 6) + (agp << 3);
          *(ushort4*)(dst) = make_ushort4(f2bf(f0.x), f2bf(f0.y), f2bf(f0.z), f2bf(f0.w));
          *(ushort4*)(dst + 4) = make_ushort4(f2bf(f1.x), f2bf(f1.y), f2bf(f1.z), f2bf(f1.w));
        }
        async16(wb + goff, (char*)Bs + ((size_t)ig << 10));
      }
      __syncthreads();
#pragma unroll
      for (int kk = 0; kk < 2; ++kk) {
        bf16x8 af[4], bfr[4];
#pragma unroll
        for (int i = 0; i < 4; ++i) {
          int row = wm + (i << 4) + m;
          int gp = ((kk << 2) + q) ^ (row & 7);
          af[i] = *(const bf16x8*)(As + (row << 6) + (gp << 3));
        }
#pragma unroll
        for (int j = 0; j < 4; ++j) {
          int row = wn + (j << 4) + m;
          int gp = ((kk << 2) + q) ^ (row & 7);
          bfr[j] = *(const bf16x8*)(Bs + (row << 6) + (gp << 3));
        }
#pragma unroll
        for (int i = 0; i < 4; ++i)
#pragma unroll
          for (int j = 0; j < 4; ++j)
            acc[i][j] = __builtin_amdgcn_mfma_f32_16x16x32_bf16(af[i], bfr[j], acc[i][j], 0, 0, 0);
      }
    }

    // epilogue: lane holds D[t = wm + i*16 + q*4 + r][o = o0 + wn + j*16 + m]
    float hb[4], vv[4];
#pragma unroll
    for (int j = 0; j < 4; ++j) {
      int o = o0 + wn + (j << 4) + m;
      hb[j] = hxb[(b << 10) + o];
      vv[j] = v[o];
    }
#pragma unroll
    for (int i = 0; i < 4; ++i) {
#pragma unroll
      for (int r = 0; r < 4; ++r) {
        float s = 0.f;
#pragma unroll
        for (int j = 0; j < 4; ++j) s += fast_tanh(acc[i][j][r] + hb[j]) * vv[j];
        s += __shfl_xor(s, 1);
        s += __shfl_xor(s, 2);
        s += __shfl_xor(s, 4);
        s += __shfl_xor(s, 8);
        if (m == 0) atomicAdd(&part[wm + (i << 4) + (q << 2) + r], s);
      }
    }
  }

  __syncthreads();  // logits complete in part[0..127]
  float e = 0.f;
  if (tid < 128) {
    e = __expf(part[tid]);
    part[tid] = e;                                   // reuse as softmax weights (unnorm)
    outs[(size_t)b * T_ + t0 + tid] = e;             // finalize divides by den
  }
  float es = e;
#pragma unroll
  for (int d = 1; d < 64; d <<= 1) es += __shfl_xor(es, d);
  if (lane == 0) atomicAdd(&den[b], es);             // waves 2,3 contribute 0
  __syncthreads();  // part[] = e^l visible to all

  // weighted sum over this block's 128 t-rows; ctx tile is L2/L3-hot (just streamed)
  int h = tid << 2;
  float s0 = 0.f, s1 = 0.f, s2 = 0.f, s3 = 0.f;
  if (PRECONV) {
    const unsigned short* cp = cb + h;
#pragma unroll 4
    for (int t = 0; t < 128; ++t) {
      uint2 u = *(const uint2*)(cp + (size_t)t * H_);
      float w = part[t];
      s0 += bf2f((unsigned short)(u.x & 0xffffu)) * w;
      s1 += bf2f((unsigned short)(u.x >> 16)) * w;
      s2 += bf2f((unsigned short)(u.y & 0xffffu)) * w;
      s3 += bf2f((unsigned short)(u.y >> 16)) * w;
    }
  } else {
    const float* cp = cf + h;
#pragma unroll 4
    for (int t = 0; t < 128; ++t) {
      float4 f = *(const float4*)(cp + (size_t)t * H_);
      float w = part[t];
      s0 += f.x * w; s1 += f.y * w; s2 += f.z * w; s3 += f.w * w;
    }
  }
  float* op = outc + (b << 10) + h;
  atomicAdd(op + 0, s0);
  atomicAdd(op + 1, s1);
  atomicAdd(op + 2, s2);
  atomicAdd(op + 3, s3);
}

// Divide numerator and unnormalized scores by den[b]. Grid (B), 256 threads.
__global__ void finalize_kernel(float* __restrict__ outc, float* __restrict__ outs,
                                const float* __restrict__ den) {
  int b = blockIdx.x, tid = threadIdx.x;
  float inv = 1.0f / den[b];
#pragma unroll
  for (int i = 0; i < 4; ++i) outc[(b << 10) + tid + (i << 8)] *= inv;
#pragma unroll
  for (int i = 0; i < 8; ++i) outs[b * T_ + tid + (i << 8)] *= inv;
}

extern "C" void kernel_launch(void* const* d_in, const int* in_sizes, int n_in,
                              void* d_out, int out_size, void* d_ws, size_t ws_size,
                              hipStream_t stream) {
  const float* x   = (const float*)d_in[0];
  const float* ctx = (const float*)d_in[1];
  // d_in[2] = mask, unused by the reference
  const float* Wq  = (const float*)d_in[3];
  const float* bq  = (const float*)d_in[4];
  const float* Wm  = (const float*)d_in[5];
  const float* bm  = (const float*)d_in[6];
  const float* v   = (const float*)d_in[7];

  float* out_c = (float*)d_out;   // [B,H]
  float* out_s = out_c + B_ * H_; // [B,T]

  char* ws = (char*)d_ws;
  float* hxb = (float*)ws;                                   // 128 KiB
  unsigned short* wmb = (unsigned short*)(ws + 131072);      // 2 MiB
  float* den = (float*)(ws + 131072 + 2097152);              // 128 B (in old 256 KiB slot)
  size_t off_ctxb = 131072 + 2097152 + 262144;
  unsigned short* ctxb = (unsigned short*)(ws + off_ctxb);   // 128 MiB
  size_t need = off_ctxb + (size_t)B_ * T_ * H_ * 2;
  bool preconv = (ws_size >= need);

  int prep_blocks = preconv ? (1312 + 32768) : 1312;
  prep_kernel<<<dim3(prep_blocks), 256, 0, stream>>>(x, Wq, bq, bm, Wm, ctx, hxb, wmb,
                                                     preconv ? ctxb : nullptr, den, out_c);
  if (preconv) {
    score_kernel<true><<<dim3(512), 256, 0, stream>>>(ctx, ctxb, wmb, hxb, v, out_s, out_c, den);
  } else {
    score_kernel<false><<<dim3(512), 256, 0, stream>>>(ctx, ctxb, wmb, hxb, v, out_s, out_c, den);
  }
  finalize_kernel<<<dim3(B_), 256, 0, stream>>>(out_c, out_s, den);
}

// Round 3
// 706.504 us; speedup vs baseline: 1.1816x; 1.1816x over previous
//
#include <hip/hip_runtime.h>
#include <math.h>

#define B_ 32
#define T_ 2048
#define H_ 1024

typedef __bf16 bf16x8 __attribute__((ext_vector_type(8)));
typedef float f32x4 __attribute__((ext_vector_type(4)));

__device__ __forceinline__ unsigned short f2bf(float f) {
  unsigned int u = __float_as_uint(f);
  u += 0x7fffu + ((u >> 16) & 1u);   // round-to-nearest-even (finite inputs)
  return (unsigned short)(u >> 16);
}

__device__ __forceinline__ float fast_tanh(float x) {
  float e = __expf(2.0f * x);
  return 1.0f - __fdividef(2.0f, e + 1.0f);  // saturates correctly at +-1
}

// Async 16B global -> LDS. LDS dest is wave-uniform base + lane*16 (HW rule).
__device__ __forceinline__ void async16(const void* g, void* l) {
  typedef const __attribute__((address_space(1))) void* gvp;
  typedef __attribute__((address_space(3))) void* lvp;
  __builtin_amdgcn_global_load_lds((gvp)(unsigned long long)g,
                                   (lvp)(unsigned int)(unsigned long long)l,
                                   16, 0, 0);
}

// blk ranges (no ctx conversion — score reads ctx fp32 directly):
//  [0,8192):     hxb — wave per (b,o): hxb[b,o] = x[b,:].Wq[o,:] + bq[o] + bm[o]
//  [8192,9216):  Wm fp32 -> bf16
//  [9216,9280):  zero logits (re-zero every launch: score atomicAdds into it)
//  [9280,9312):  zero out_c  (re-zero every launch: wsum atomicAdds into it)
__global__ void prep_kernel(const float* __restrict__ x, const float* __restrict__ Wq,
                            const float* __restrict__ bq, const float* __restrict__ bm,
                            const float* __restrict__ Wm,
                            float* __restrict__ hxb, unsigned short* __restrict__ wmb,
                            float* __restrict__ logits, float* __restrict__ outc) {
  int blk = blockIdx.x, tid = threadIdx.x;
  if (blk < 8192) {
    int wave = tid >> 6, lane = tid & 63;
    int pair = (blk << 2) + wave;        // (b,o) pair
    int b = pair >> 10, o = pair & (H_ - 1);
    const float4* wr = (const float4*)(Wq + (size_t)o * H_);
    const float4* xr = (const float4*)(x + (size_t)b * H_);
    float s = 0.f;
#pragma unroll
    for (int s4 = 0; s4 < 4; ++s4) {
      float4 wv = wr[(s4 << 6) + lane];
      float4 xv = xr[(s4 << 6) + lane];
      s += wv.x * xv.x + wv.y * xv.y + wv.z * xv.z + wv.w * xv.w;
    }
#pragma unroll
    for (int d = 1; d < 64; d <<= 1) s += __shfl_xor(s, d);
    if (lane == 0) hxb[(b << 10) + o] = s + bq[o] + bm[o];
  } else if (blk < 9216) {
    int i = ((blk - 8192) << 10) + (tid << 2);
    float4 wv = *(const float4*)(Wm + i);
    *(ushort4*)(wmb + i) = make_ushort4(f2bf(wv.x), f2bf(wv.y), f2bf(wv.z), f2bf(wv.w));
  } else if (blk < 9280) {
    int zb = blk - 9216;
    *(float4*)(logits + (zb << 10) + (tid << 2)) = (float4){0.f, 0.f, 0.f, 0.f};
  } else {
    int zb = blk - 9280;
    *(float4*)(outc + (zb << 10) + (tid << 2)) = (float4){0.f, 0.f, 0.f, 0.f};
  }
}

// Grid 4096: blockIdx.x = g*8 + oc, g = b*16 + tb. One 128t x 128o tile per block.
// A staged from ctx fp32 with inline bf16 convert into XOR-swizzled LDS; B (Wm bf16)
// staged via global_load_lds with the same swizzle (phys granule = logical ^ (row&7)).
// g-major order: the 8 blocks sharing a ctx tile run concurrently on the 8 XCDs ->
// one HBM fetch + L3 hits; Wm o-chunk oc is only touched by XCD oc -> L2-resident.
// Partial logits atomicAdd'ed to global; consumer is a separate kernel (kernel
// boundary = safe cross-XCD ordering).
__global__ __launch_bounds__(256) void score_kernel(
    const float* __restrict__ ctx, const unsigned short* __restrict__ wmb,
    const float* __restrict__ hxb, const float* __restrict__ v,
    float* __restrict__ logits) {
  __shared__ __align__(16) unsigned short As[128 * 64];
  __shared__ __align__(16) unsigned short Bs[128 * 64];
  __shared__ float part[128];

  int tid = threadIdx.x;
  int bx = blockIdx.x;
  int g = bx >> 3;            // (b, t-tile) group 0..511
  int oc = bx & 7;            // o-chunk 0..7
  int b = g >> 4;
  int t0 = (g & 15) << 7;
  int o0 = oc << 7;
  if (tid < 128) part[tid] = 0.f;

  int lane = tid & 63;
  int wave = tid >> 6;
  int wm = (wave >> 1) << 6;  // wave t-offset (0/64)
  int wn = (wave & 1) << 6;   // wave o-offset (0/64)
  int q = lane >> 4;
  int m = lane & 15;

  const float* cf = ctx + ((size_t)b * T_ + t0) * H_;
  const unsigned short* wb = wmb + (size_t)o0 * H_;

  f32x4 acc[4][4];
#pragma unroll
  for (int i = 0; i < 4; ++i)
#pragma unroll
    for (int j = 0; j < 4; ++j) acc[i][j] = (f32x4){0.f, 0.f, 0.f, 0.f};

  for (int k0 = 0; k0 < H_; k0 += 64) {
    __syncthreads();
#pragma unroll
    for (int i = 0; i < 4; ++i) {
      // B tile: async global->LDS in swizzled physical order
      int ig = (wave << 2) + i;          // issue-group 0..15 (64 granules each)
      int p = (ig << 6) + lane;          // physical granule 0..1023
      int row = p >> 3;
      int gl = (p & 7) ^ (row & 7);      // logical granule (swizzle inverse)
      size_t goff = (size_t)row * H_ + k0 + (gl << 3);
      async16(wb + goff, (char*)Bs + ((size_t)ig << 10));
      // A tile: manual fp32 load + convert into the same swizzled layout
      int arow = (tid >> 3) + (i << 5);
      int agl = tid & 7;                 // logical granule
      int agp = agl ^ (arow & 7);        // physical granule
      const float* src = cf + (size_t)arow * H_ + k0 + (agl << 3);
      float4 f0 = *(const float4*)(src);
      float4 f1 = *(const float4*)(src + 4);
      unsigned short* dst = As + (arow << 6) + (agp << 3);
      *(ushort4*)(dst) = make_ushort4(f2bf(f0.x), f2bf(f0.y), f2bf(f0.z), f2bf(f0.w));
      *(ushort4*)(dst + 4) = make_ushort4(f2bf(f1.x), f2bf(f1.y), f2bf(f1.z), f2bf(f1.w));
    }
    __syncthreads();
#pragma unroll
    for (int kk = 0; kk < 2; ++kk) {
      bf16x8 af[4], bfr[4];
#pragma unroll
      for (int i = 0; i < 4; ++i) {
        int row = wm + (i << 4) + m;
        int gp = ((kk << 2) + q) ^ (row & 7);
        af[i] = *(const bf16x8*)(As + (row << 6) + (gp << 3));
      }
#pragma unroll
      for (int j = 0; j < 4; ++j) {
        int row = wn + (j << 4) + m;
        int gp = ((kk << 2) + q) ^ (row & 7);
        bfr[j] = *(const bf16x8*)(Bs + (row << 6) + (gp << 3));
      }
#pragma unroll
      for (int i = 0; i < 4; ++i)
#pragma unroll
        for (int j = 0; j < 4; ++j)
          acc[i][j] = __builtin_amdgcn_mfma_f32_16x16x32_bf16(af[i], bfr[j], acc[i][j], 0, 0, 0);
    }
  }

  // epilogue: lane holds D[t = wm + i*16 + q*4 + r][o = o0 + wn + j*16 + m]
  float hb[4], vv[4];
#pragma unroll
  for (int j = 0; j < 4; ++j) {
    int o = o0 + wn + (j << 4) + m;
    hb[j] = hxb[(b << 10) + o];
    vv[j] = v[o];
  }
#pragma unroll
  for (int i = 0; i < 4; ++i) {
#pragma unroll
    for (int r = 0; r < 4; ++r) {
      float s = 0.f;
#pragma unroll
      for (int j = 0; j < 4; ++j) s += fast_tanh(acc[i][j][r] + hb[j]) * vv[j];
      s += __shfl_xor(s, 1);
      s += __shfl_xor(s, 2);
      s += __shfl_xor(s, 4);
      s += __shfl_xor(s, 8);
      if (m == 0) atomicAdd(&part[wm + (i << 4) + (q << 2) + r], s);
    }
  }
  __syncthreads();
  if (tid < 128) atomicAdd(&logits[b * T_ + t0 + tid], part[tid]);
}

// Softmax + weighted sum (round-0 validated structure, fp32 ctx, 64-row chunks).
// Grid (T/64, B). Each block recomputes the row softmax from logits (8 KB),
// handles a 64-t chunk; thread owns 4 h columns.
__global__ void wsum_kernel(const float* __restrict__ ctx,
                            const float* __restrict__ logits,
                            float* __restrict__ score, float* __restrict__ outc) {
  int tid = threadIdx.x;
  int b = blockIdx.y;
  int tc = blockIdx.x << 6;
  __shared__ float wred[4];
  __shared__ float sc[64];

  const float* lb = logits + b * T_;
  float l[8];
  float mx = -3.4e38f;
#pragma unroll
  for (int i = 0; i < 8; ++i) { l[i] = lb[tid + (i << 8)]; mx = fmaxf(mx, l[i]); }
#pragma unroll
  for (int d = 1; d < 64; d <<= 1) mx = fmaxf(mx, __shfl_xor(mx, d));
  if ((tid & 63) == 0) wred[tid >> 6] = mx;
  __syncthreads();
  mx = fmaxf(fmaxf(wred[0], wred[1]), fmaxf(wred[2], wred[3]));
  __syncthreads();
  float e[8];
  float se = 0.f;
#pragma unroll
  for (int i = 0; i < 8; ++i) { e[i] = __expf(l[i] - mx); se += e[i]; }
#pragma unroll
  for (int d = 1; d < 64; d <<= 1) se += __shfl_xor(se, d);
  if ((tid & 63) == 0) wred[tid >> 6] = se;
  __syncthreads();
  se = wred[0] + wred[1] + wred[2] + wred[3];
  float inv = 1.0f / se;
#pragma unroll
  for (int i = 0; i < 8; ++i) {
    int tg = tid + (i << 8);
    if ((tg >> 6) == (int)blockIdx.x) sc[tg & 63] = e[i] * inv;
  }
  if (blockIdx.x == 0) {
#pragma unroll
    for (int i = 0; i < 8; ++i) score[b * T_ + tid + (i << 8)] = e[i] * inv;
  }
  __syncthreads();

  int h = tid << 2;
  const float* cp = ctx + ((size_t)b * T_ + tc) * H_ + h;
  float s0 = 0.f, s1 = 0.f, s2 = 0.f, s3 = 0.f;
#pragma unroll 4
  for (int t = 0; t < 64; ++t) {
    float4 f = *(const float4*)(cp + (size_t)t * H_);
    float w = sc[t];
    s0 += f.x * w; s1 += f.y * w; s2 += f.z * w; s3 += f.w * w;
  }
  float* op = outc + (b << 10) + h;
  atomicAdd(op + 0, s0);
  atomicAdd(op + 1, s1);
  atomicAdd(op + 2, s2);
  atomicAdd(op + 3, s3);
}

extern "C" void kernel_launch(void* const* d_in, const int* in_sizes, int n_in,
                              void* d_out, int out_size, void* d_ws, size_t ws_size,
                              hipStream_t stream) {
  const float* x   = (const float*)d_in[0];
  const float* ctx = (const float*)d_in[1];
  // d_in[2] = mask, unused by the reference
  const float* Wq  = (const float*)d_in[3];
  const float* bq  = (const float*)d_in[4];
  const float* Wm  = (const float*)d_in[5];
  const float* bm  = (const float*)d_in[6];
  const float* v   = (const float*)d_in[7];

  float* out_c = (float*)d_out;   // [B,H]
  float* out_s = out_c + B_ * H_; // [B,T]

  // workspace: ~2.5 MiB total
  char* ws = (char*)d_ws;
  float* hxb = (float*)ws;                                        // 128 KiB
  unsigned short* wmb = (unsigned short*)(ws + 131072);           // 2 MiB
  float* logits = (float*)(ws + 131072 + 2097152);                // 256 KiB

  prep_kernel<<<dim3(9312), 256, 0, stream>>>(x, Wq, bq, bm, Wm, hxb, wmb,
                                              logits, out_c);
  score_kernel<<<dim3(4096), 256, 0, stream>>>(ctx, wmb, hxb, v, logits);
  wsum_kernel<<<dim3(T_ / 64, B_), 256, 0, stream>>>(ctx, logits, out_s, out_c);
}

// Round 4
// 642.706 us; speedup vs baseline: 1.2989x; 1.0993x over previous
//
#include <hip/hip_runtime.h>
#include <math.h>

#define B_ 32
#define T_ 2048
#define H_ 1024

typedef __bf16 bf16x8 __attribute__((ext_vector_type(8)));
typedef float f32x4 __attribute__((ext_vector_type(4)));

__device__ __forceinline__ unsigned short f2bf(float f) {
  unsigned int u = __float_as_uint(f);
  u += 0x7fffu + ((u >> 16) & 1u);   // round-to-nearest-even (finite inputs)
  return (unsigned short)(u >> 16);
}

__device__ __forceinline__ float bf2f(unsigned short s) {
  return __uint_as_float(((unsigned int)s) << 16);
}

__device__ __forceinline__ float fast_tanh(float x) {
  float e = __expf(2.0f * x);
  return 1.0f - __fdividef(2.0f, e + 1.0f);  // saturates correctly at +-1
}

// Async 16B global -> LDS. LDS dest is wave-uniform base + lane*16 (HW rule).
__device__ __forceinline__ void async16(const void* g, void* l) {
  typedef const __attribute__((address_space(1))) void* gvp;
  typedef __attribute__((address_space(3))) void* lvp;
  __builtin_amdgcn_global_load_lds((gvp)(unsigned long long)g,
                                   (lvp)(unsigned int)(unsigned long long)l,
                                   16, 0, 0);
}

// Re-blocked prep: FEW blocks, LOTS of work each (prep was dispatch-bound at
// 42k x 8KB blocks ~350us; now 2584 x 32-128KB blocks).
// blk ranges:
//  [0,2048):      ctx fp32 -> bf16, 32768 floats/block (16 iters x 256thr x 8)
//  [2048,2304):   hxb — wave per o: Wq row loaded ONCE, loop over b
//  [2304,2560):   Wm fp32 -> bf16, 4096 floats/block
//  [2560,2576):   zero logits (4096 floats/block)
//  [2576,2584):   zero out_c  (4096 floats/block)
__global__ void prep_kernel(const float* __restrict__ x, const float* __restrict__ Wq,
                            const float* __restrict__ bq, const float* __restrict__ bm,
                            const float* __restrict__ Wm, const float* __restrict__ ctx,
                            float* __restrict__ hxb, unsigned short* __restrict__ wmb,
                            unsigned short* __restrict__ ctxb,
                            float* __restrict__ logits, float* __restrict__ outc) {
  int blk = blockIdx.x, tid = threadIdx.x;
  if (blk < 2048) {
    if (ctxb == nullptr) return;
    size_t base = ((size_t)blk << 15) + ((size_t)tid << 3);
#pragma unroll 4
    for (int it = 0; it < 16; ++it) {
      size_t i = base + ((size_t)it << 11);
      float4 a = *(const float4*)(ctx + i);
      float4 c = *(const float4*)(ctx + i + 4);
      *(ushort4*)(ctxb + i) = make_ushort4(f2bf(a.x), f2bf(a.y), f2bf(a.z), f2bf(a.w));
      *(ushort4*)(ctxb + i + 4) = make_ushort4(f2bf(c.x), f2bf(c.y), f2bf(c.z), f2bf(c.w));
    }
  } else if (blk < 2304) {
    int wave = tid >> 6, lane = tid & 63;
    int o = ((blk - 2048) << 2) + wave;
    const float4* wr = (const float4*)(Wq + (size_t)o * H_);
    float4 wv[4];
#pragma unroll
    for (int s4 = 0; s4 < 4; ++s4) wv[s4] = wr[(s4 << 6) + lane];
    float bias = bq[o] + bm[o];
#pragma unroll 4
    for (int b = 0; b < B_; ++b) {
      const float4* xr = (const float4*)(x + (size_t)b * H_);
      float s = 0.f;
#pragma unroll
      for (int s4 = 0; s4 < 4; ++s4) {
        float4 xv = xr[(s4 << 6) + lane];
        s += wv[s4].x * xv.x + wv[s4].y * xv.y + wv[s4].z * xv.z + wv[s4].w * xv.w;
      }
#pragma unroll
      for (int d = 1; d < 64; d <<= 1) s += __shfl_xor(s, d);
      if (lane == 0) hxb[(b << 10) + o] = s + bias;
    }
  } else if (blk < 2560) {
    int i0 = ((blk - 2304) << 12) + (tid << 2);
#pragma unroll
    for (int it = 0; it < 4; ++it) {
      int i = i0 + (it << 10);
      float4 wv = *(const float4*)(Wm + i);
      *(ushort4*)(wmb + i) = make_ushort4(f2bf(wv.x), f2bf(wv.y), f2bf(wv.z), f2bf(wv.w));
    }
  } else if (blk < 2576) {
    int i0 = ((blk - 2560) << 12) + (tid << 2);
#pragma unroll
    for (int it = 0; it < 4; ++it)
      *(float4*)(logits + i0 + (it << 10)) = (float4){0.f, 0.f, 0.f, 0.f};
  } else {
    int i0 = ((blk - 2576) << 12) + (tid << 2);
#pragma unroll
    for (int it = 0; it < 4; ++it)
      *(float4*)(outc + i0 + (it << 10)) = (float4){0.f, 0.f, 0.f, 0.f};
  }
}

// Grid 4096: blockIdx.x = ot*512 + b*16 + tt. One 128t x 128o tile per block.
// A (ctx bf16) and B (Wm bf16) staged via global_load_lds with XOR swizzle:
// physical 16B-granule g_phys = g_log ^ (row & 7) -> b128 frag reads hit the
// 8-access/bank LDS floor (conflict-free). Partial logits atomicAdd'ed to global.
// (round-0 verified version, 255us)
template <bool PRECONV>
__global__ __launch_bounds__(256) void score_kernel(
    const float* __restrict__ ctxf, const unsigned short* __restrict__ ctxb,
    const unsigned short* __restrict__ wmb,
    const float* __restrict__ hxb, const float* __restrict__ v,
    float* logits) {
  __shared__ __align__(16) unsigned short As[128 * 64];
  __shared__ __align__(16) unsigned short Bs[128 * 64];
  __shared__ float part[128];

  int tid = threadIdx.x;
  int xx = blockIdx.x;
  int ot = xx >> 9;
  int bt = xx & 511;
  int b = bt >> 4;
  int t0 = (bt & 15) << 7;
  int o0 = ot << 7;
  if (tid < 128) part[tid] = 0.f;

  int lane = tid & 63;
  int wave = tid >> 6;
  int wm = (wave >> 1) << 6;  // wave t-offset (0/64)
  int wn = (wave & 1) << 6;   // wave o-offset (0/64)
  int q = lane >> 4;
  int m = lane & 15;

  const unsigned short* cb = PRECONV ? (ctxb + ((size_t)b * T_ + t0) * H_) : nullptr;
  const float* cf = PRECONV ? nullptr : (ctxf + ((size_t)b * T_ + t0) * H_);
  const unsigned short* wb = wmb + (size_t)o0 * H_;

  f32x4 acc[4][4];
#pragma unroll
  for (int i = 0; i < 4; ++i)
#pragma unroll
    for (int j = 0; j < 4; ++j) acc[i][j] = (f32x4){0.f, 0.f, 0.f, 0.f};

  for (int k0 = 0; k0 < H_; k0 += 64) {
    __syncthreads();
#pragma unroll
    for (int i = 0; i < 4; ++i) {
      int ig = (wave << 2) + i;          // issue-group 0..15 (64 granules each)
      int p = (ig << 6) + lane;          // physical granule 0..1023
      int row = p >> 3;
      int gl = (p & 7) ^ (row & 7);      // logical granule (swizzle inverse)
      size_t goff = (size_t)row * H_ + k0 + (gl << 3);
      if (PRECONV) {
        async16(cb + goff, (char*)As + ((size_t)ig << 10));
      } else {
        // manual convert staging into the same swizzled layout
        int arow = (tid >> 3) + (i << 5);
        int agl = tid & 7;
        int agp = agl ^ (arow & 7);
        const float* src = cf + (size_t)arow * H_ + k0 + (agl << 3);
        float4 f0 = *(const float4*)(src);
        float4 f1 = *(const float4*)(src + 4);
        unsigned short* dst = As + (arow << 6) + (agp << 3);
        *(ushort4*)(dst) = make_ushort4(f2bf(f0.x), f2bf(f0.y), f2bf(f0.z), f2bf(f0.w));
        *(ushort4*)(dst + 4) = make_ushort4(f2bf(f1.x), f2bf(f1.y), f2bf(f1.z), f2bf(f1.w));
      }
      async16(wb + goff, (char*)Bs + ((size_t)ig << 10));
    }
    __syncthreads();
#pragma unroll
    for (int kk = 0; kk < 2; ++kk) {
      bf16x8 af[4], bfr[4];
#pragma unroll
      for (int i = 0; i < 4; ++i) {
        int row = wm + (i << 4) + m;
        int gp = ((kk << 2) + q) ^ (row & 7);
        af[i] = *(const bf16x8*)(As + (row << 6) + (gp << 3));
      }
#pragma unroll
      for (int j = 0; j < 4; ++j) {
        int row = wn + (j << 4) + m;
        int gp = ((kk << 2) + q) ^ (row & 7);
        bfr[j] = *(const bf16x8*)(Bs + (row << 6) + (gp << 3));
      }
#pragma unroll
      for (int i = 0; i < 4; ++i)
#pragma unroll
        for (int j = 0; j < 4; ++j)
          acc[i][j] = __builtin_amdgcn_mfma_f32_16x16x32_bf16(af[i], bfr[j], acc[i][j], 0, 0, 0);
    }
  }

  // epilogue: lane holds D[t = wm + i*16 + q*4 + r][o = o0 + wn + j*16 + m]
  float hb[4], vv[4];
#pragma unroll
  for (int j = 0; j < 4; ++j) {
    int o = o0 + wn + (j << 4) + m;
    hb[j] = hxb[(b << 10) + o];
    vv[j] = v[o];
  }
#pragma unroll
  for (int i = 0; i < 4; ++i) {
#pragma unroll
    for (int r = 0; r < 4; ++r) {
      float s = 0.f;
#pragma unroll
      for (int j = 0; j < 4; ++j) s += fast_tanh(acc[i][j][r] + hb[j]) * vv[j];
      s += __shfl_xor(s, 1);
      s += __shfl_xor(s, 2);
      s += __shfl_xor(s, 4);
      s += __shfl_xor(s, 8);
      if (m == 0) atomicAdd(&part[wm + (i << 4) + (q << 2) + r], s);
    }
  }
  __syncthreads();
  if (tid < 128) atomicAdd(&logits[b * T_ + t0 + tid], part[tid]);
}

// Fused softmax + weighted sum (round-0 verified). Grid (T/128, B). Each block
// recomputes the row softmax from logits (8 KB), handles a 128-t chunk.
template <bool PRECONV>
__global__ void wsum_kernel(const float* __restrict__ ctxf, const unsigned short* __restrict__ ctxb,
                            const float* __restrict__ logits,
                            float* __restrict__ score, float* __restrict__ outc) {
  int tid = threadIdx.x;
  int b = blockIdx.y;
  int tc = blockIdx.x << 7;
  __shared__ float wred[4];
  __shared__ float sc[128];

  const float* lb = logits + b * T_;
  float l[8];
  float mx = -3.4e38f;
#pragma unroll
  for (int i = 0; i < 8; ++i) { l[i] = lb[tid + (i << 8)]; mx = fmaxf(mx, l[i]); }
#pragma unroll
  for (int d = 1; d < 64; d <<= 1) mx = fmaxf(mx, __shfl_xor(mx, d));
  if ((tid & 63) == 0) wred[tid >> 6] = mx;
  __syncthreads();
  mx = fmaxf(fmaxf(wred[0], wred[1]), fmaxf(wred[2], wred[3]));
  __syncthreads();
  float e[8];
  float se = 0.f;
#pragma unroll
  for (int i = 0; i < 8; ++i) { e[i] = __expf(l[i] - mx); se += e[i]; }
#pragma unroll
  for (int d = 1; d < 64; d <<= 1) se += __shfl_xor(se, d);
  if ((tid & 63) == 0) wred[tid >> 6] = se;
  __syncthreads();
  se = wred[0] + wred[1] + wred[2] + wred[3];
  float inv = 1.0f / se;
#pragma unroll
  for (int i = 0; i < 8; ++i) {
    int tg = tid + (i << 8);
    if ((tg >> 7) == (int)blockIdx.x) sc[tg & 127] = e[i] * inv;
  }
  if (blockIdx.x == 0) {
#pragma unroll
    for (int i = 0; i < 8; ++i) score[b * T_ + tid + (i << 8)] = e[i] * inv;
  }
  __syncthreads();

  int h = tid << 2;
  float s0 = 0.f, s1 = 0.f, s2 = 0.f, s3 = 0.f;
  if (PRECONV) {
    const unsigned short* cp = ctxb + ((size_t)b * T_ + tc) * H_ + h;
#pragma unroll 4
    for (int t = 0; t < 128; ++t) {
      uint2 u = *(const uint2*)(cp + (size_t)t * H_);
      float w = sc[t];
      s0 += bf2f((unsigned short)(u.x & 0xffffu)) * w;
      s1 += bf2f((unsigned short)(u.x >> 16)) * w;
      s2 += bf2f((unsigned short)(u.y & 0xffffu)) * w;
      s3 += bf2f((unsigned short)(u.y >> 16)) * w;
    }
  } else {
    const float* cp = ctxf + ((size_t)b * T_ + tc) * H_ + h;
#pragma unroll 4
    for (int t = 0; t < 128; ++t) {
      float4 f = *(const float4*)(cp + (size_t)t * H_);
      float w = sc[t];
      s0 += f.x * w; s1 += f.y * w; s2 += f.z * w; s3 += f.w * w;
    }
  }
  float* op = outc + (b << 10) + h;
  atomicAdd(op + 0, s0);
  atomicAdd(op + 1, s1);
  atomicAdd(op + 2, s2);
  atomicAdd(op + 3, s3);
}

extern "C" void kernel_launch(void* const* d_in, const int* in_sizes, int n_in,
                              void* d_out, int out_size, void* d_ws, size_t ws_size,
                              hipStream_t stream) {
  const float* x   = (const float*)d_in[0];
  const float* ctx = (const float*)d_in[1];
  // d_in[2] = mask, unused by the reference
  const float* Wq  = (const float*)d_in[3];
  const float* bq  = (const float*)d_in[4];
  const float* Wm  = (const float*)d_in[5];
  const float* bm  = (const float*)d_in[6];
  const float* v   = (const float*)d_in[7];

  float* out_c = (float*)d_out;   // [B,H]
  float* out_s = out_c + B_ * H_; // [B,T]

  char* ws = (char*)d_ws;
  float* hxb = (float*)ws;                                   // 128 KiB
  unsigned short* wmb = (unsigned short*)(ws + 131072);      // 2 MiB
  float* logits = (float*)(ws + 131072 + 2097152);           // 256 KiB
  size_t off_ctxb = 131072 + 2097152 + 262144;
  unsigned short* ctxb = (unsigned short*)(ws + off_ctxb);   // 128 MiB
  size_t need = off_ctxb + (size_t)B_ * T_ * H_ * 2;
  bool preconv = (ws_size >= need);

  prep_kernel<<<dim3(2584), 256, 0, stream>>>(x, Wq, bq, bm, Wm, ctx, hxb, wmb,
                                              preconv ? ctxb : nullptr, logits, out_c);
  if (preconv) {
    score_kernel<true><<<dim3(4096), 256, 0, stream>>>(ctx, ctxb, wmb, hxb, v, logits);
    wsum_kernel<true><<<dim3(T_ / 128, B_), 256, 0, stream>>>(ctx, ctxb, logits, out_s, out_c);
  } else {
    score_kernel<false><<<dim3(4096), 256, 0, stream>>>(ctx, ctxb, wmb, hxb, v, logits);
    wsum_kernel<false><<<dim3(T_ / 128, B_), 256, 0, stream>>>(ctx, ctxb, logits, out_s, out_c);
  }
}